// Round 11
// baseline (226.560 us; speedup 1.0000x reference)
//
#include <hip/hip_runtime.h>
#include <hip/hip_bf16.h>
#include <hip/hip_cooperative_groups.h>
#include <math.h>

namespace cg = cooperative_groups;

#define NHEADS   32
#define CONV_DIM 2304
#define D_INNER  2048
#define SEQLEN   1024
#define NROWS    2048     // BATCH*SEQLEN
#define ZX_STR   4352     // z(2048) + xBC(2304); dt columns handled separately
#define D_MODEL  1024
#define Q        64       // chunk length
#define NCHUNK   16       // SEQLEN / Q
#define XT_STR   72       // LDS transpose row stride (shorts): 144B = 16B-aligned

typedef __attribute__((ext_vector_type(8))) short bhalf8;
typedef __attribute__((ext_vector_type(8))) short short8;
typedef __attribute__((ext_vector_type(2))) short short2v;
typedef __attribute__((ext_vector_type(4))) short short4v;
typedef __attribute__((ext_vector_type(4))) float f32x4;

__device__ __forceinline__ float bf2f(__hip_bfloat16 v){ return __bfloat162float(v); }
__device__ __forceinline__ short f2bs(float f){ __hip_bfloat16 h = __float2bfloat16(f); return *(short*)&h; }
__device__ __forceinline__ float s2f(short s){ __hip_bfloat16 h = *(__hip_bfloat16*)&s; return __bfloat162float(h); }
__device__ __forceinline__ float rdin(const void* p, size_t i, int isf){
    return isf ? ((const float*)p)[i] : __bfloat162float(((const __hip_bfloat16*)p)[i]);
}

// ---------------------------------------------------------------------------
// Fused normalize pass with INLINE dtype vote.
// x / in_proj_w -> bf16; out_proj_w -> bf16 * norm_w[k] (norm folded).
// ---------------------------------------------------------------------------
#define XN8 262144   // 2048*1024/8
#define WN8 561152   // 4384*1024/8
#define ON8 262144   // 1024*2048/8
__global__ __launch_bounds__(256)
void to_bf16_all(const void* __restrict__ xs, const void* __restrict__ ws,
                 const void* __restrict__ os, const void* __restrict__ normw,
                 __hip_bfloat16* __restrict__ xd, __hip_bfloat16* __restrict__ wd,
                 __hip_bfloat16* __restrict__ od, int* __restrict__ flagp)
{
    const unsigned short* xu = (const unsigned short*)xs;
    int cnt = 0;
    for (int k = threadIdx.x; k < 4096; k += 256) {
        int e = (xu[2 * k] >> 7) & 0xFF;
        cnt += (e >= 90 && e <= 141) ? 1 : 0;
    }
#pragma unroll
    for (int m = 1; m < 64; m <<= 1) cnt += __shfl_xor(cnt, m);
    __shared__ int red[4];
    if ((threadIdx.x & 63) == 0) red[threadIdx.x >> 6] = cnt;
    __syncthreads();
    const int isf = ((red[0] + red[1] + red[2] + red[3]) < 2048) ? 1 : 0;
    if (blockIdx.x == 0 && threadIdx.x == 0) *flagp = isf;

    int i = blockIdx.x * 256 + threadIdx.x;
    if (i < XN8 + WN8) {
        const void* src; __hip_bfloat16* dst; int j;
        if (i < XN8) { src = xs; dst = xd; j = i; }
        else         { src = ws; dst = wd; j = i - XN8; }
        if (isf) {
            const float4* s = (const float4*)src;
            float4 a = s[2 * j], b = s[2 * j + 1];
            short8 r;
            r[0]=f2bs(a.x); r[1]=f2bs(a.y); r[2]=f2bs(a.z); r[3]=f2bs(a.w);
            r[4]=f2bs(b.x); r[5]=f2bs(b.y); r[6]=f2bs(b.z); r[7]=f2bs(b.w);
            ((short8*)dst)[j] = r;
        } else {
            ((float4*)dst)[j] = ((const float4*)src)[j];
        }
    } else {
        int j = i - XN8 - WN8;
        int k0 = (j * 8) & (D_INNER - 1);
        float v[8];
        if (isf) {
            const float4* s = (const float4*)os;
            float4 a = s[2 * j], b = s[2 * j + 1];
            v[0]=a.x; v[1]=a.y; v[2]=a.z; v[3]=a.w;
            v[4]=b.x; v[5]=b.y; v[6]=b.z; v[7]=b.w;
        } else {
            bhalf8 a = ((const bhalf8*)os)[j];
#pragma unroll
            for (int q = 0; q < 8; ++q) v[q] = s2f(a[q]);
        }
        short8 r;
#pragma unroll
        for (int q = 0; q < 8; ++q)
            r[q] = f2bs(v[q] * rdin(normw, k0 + q, isf));
        ((short8*)od)[j] = r;
    }
}

// ---------------------------------------------------------------------------
// GEMM C[m,n] = sum_k A[m,k]*W[n,k]. XOR-swizzled LDS (16B segments).
// MODE 0: bf16 store. MODE 1: acc*rsqrt(rowsum[m]/2048+eps) + raw-x residual.
// ---------------------------------------------------------------------------
template<int MODE, int MT, int NT, int WROWS, int WCOLS>
__global__ __launch_bounds__(256)
void gemm_bt(const __hip_bfloat16* __restrict__ A,
             const __hip_bfloat16* __restrict__ W,
             __hip_bfloat16* __restrict__ Cb,
             const void* __restrict__ xraw,
             void* __restrict__ outv,
             const float* __restrict__ rowsum,
             const int* __restrict__ flagp,
             int K, int N)
{
    constexpr int FM = MT / WROWS / 16;
    constexpr int FN = NT / WCOLS / 16;
    constexpr int AI = MT / 32;
    constexpr int BI = NT / 32;
    __shared__ short As[MT * 64];
    __shared__ short Bs[NT * 64];
    const int m0 = blockIdx.y * MT;
    const int n0 = blockIdx.x * NT;
    const int wave = threadIdx.x >> 6;
    const int lane = threadIdx.x & 63;
    const int lr8 = lane >> 3, lc8 = lane & 7;
    const int lr  = lane & 15, lq  = lane >> 4;
    const int wm = (wave / WCOLS) * (MT / WROWS);
    const int wn = (wave % WCOLS) * (NT / WCOLS);
    const int swl = lr & 7;

    f32x4 acc[FM][FN];
#pragma unroll
    for (int i = 0; i < FM; ++i)
#pragma unroll
        for (int j = 0; j < FN; ++j) acc[i][j] = (f32x4){0.f,0.f,0.f,0.f};

    for (int k0 = 0; k0 < K; k0 += 64) {
#pragma unroll
        for (int i = 0; i < AI; ++i) {
            const int rt = (wave * AI + i) * 8;
            const __hip_bfloat16* gp = A + (size_t)(m0 + rt + lr8) * K + k0 + ((lc8 ^ lr8) << 3);
            __builtin_amdgcn_global_load_lds(
                (const __attribute__((address_space(1))) void*)gp,
                (__attribute__((address_space(3))) void*)&As[rt * 64], 16, 0, 0);
        }
#pragma unroll
        for (int i = 0; i < BI; ++i) {
            const int rt = (wave * BI + i) * 8;
            const __hip_bfloat16* gp = W + (size_t)(n0 + rt + lr8) * K + k0 + ((lc8 ^ lr8) << 3);
            __builtin_amdgcn_global_load_lds(
                (const __attribute__((address_space(1))) void*)gp,
                (__attribute__((address_space(3))) void*)&Bs[rt * 64], 16, 0, 0);
        }
        __syncthreads();
#pragma unroll
        for (int kk = 0; kk < 64; kk += 32) {
            const int sw = (((kk >> 3) + lq) ^ swl) << 3;
            bhalf8 af[FM], bfv[FN];
#pragma unroll
            for (int t = 0; t < FM; ++t)
                af[t]  = *(const bhalf8*)&As[(wm + t * 16 + lr) * 64 + sw];
#pragma unroll
            for (int t = 0; t < FN; ++t)
                bfv[t] = *(const bhalf8*)&Bs[(wn + t * 16 + lr) * 64 + sw];
#pragma unroll
            for (int ti = 0; ti < FM; ++ti)
#pragma unroll
                for (int tj = 0; tj < FN; ++tj)
                    acc[ti][tj] = __builtin_amdgcn_mfma_f32_16x16x32_bf16(
                        af[ti], bfv[tj], acc[ti][tj], 0, 0, 0);
        }
        __syncthreads();
    }

    const int isf = (MODE == 1) ? *flagp : 0;
#pragma unroll
    for (int ti = 0; ti < FM; ++ti)
#pragma unroll
        for (int tj = 0; tj < FN; ++tj)
#pragma unroll
            for (int r = 0; r < 4; ++r) {
                int m = m0 + wm + ti * 16 + lq * 4 + r;
                int n = n0 + wn + tj * 16 + lr;
                size_t idx = (size_t)m * N + n;
                float v = acc[ti][tj][r];
                if (MODE == 0) {
                    Cb[idx] = __float2bfloat16(v);
                } else {
                    float scale = rsqrtf(rowsum[m] / (float)D_INNER + 1e-5f);
                    v = v * scale + rdin(xraw, idx, isf);
                    if (isf) ((float*)outv)[idx] = v;
                    else     ((__hip_bfloat16*)outv)[idx] = __float2bfloat16(v);
                }
            }
}

// ---------------------------------------------------------------------------
// MERGED conv+dt kernel, grid 512 (unchanged — known good).
// ---------------------------------------------------------------------------
__global__ __launch_bounds__(256)
void convdt(const __hip_bfloat16* __restrict__ zxb,
            const void* __restrict__ conv_w, const void* __restrict__ conv_b,
            const void* __restrict__ xraw, const void* __restrict__ wraw,
            const void* __restrict__ dt_bias,
            const int* __restrict__ flagp,
            __hip_bfloat16* __restrict__ xs_bf,
            __hip_bfloat16* __restrict__ B_bf,
            __hip_bfloat16* __restrict__ C_bf,
            float* __restrict__ dtp)
{
    __shared__ short smem[11 * CONV_DIM];
    const int isf = *flagp;

    if (blockIdx.x < 256) {
        const int r0 = blockIdx.x * 8;
        const int bstart = r0 & ~(SEQLEN - 1);
        for (int idx = threadIdx.x; idx < 11 * (CONV_DIM / 8); idx += 256) {
            int ii = idx / (CONV_DIM / 8);
            int seg = idx % (CONV_DIM / 8);
            int g = r0 - 3 + ii;
            bhalf8 v;
            if (g >= bstart) {
                v = *(const bhalf8*)&zxb[(size_t)g * ZX_STR + 2048 + seg * 8];
            } else {
#pragma unroll
                for (int j = 0; j < 8; ++j) v[j] = 0;
            }
            *(bhalf8*)&smem[ii * CONV_DIM + seg * 8] = v;
        }
        __syncthreads();

#pragma unroll
        for (int sIt = 0; sIt < 2; ++sIt) {
            const int seg = threadIdx.x + sIt * 256;
            if (seg >= CONV_DIM / 8) break;
            const int c0 = seg * 8;
            float wt[8][4], bias[8];
            if (isf) {
                const float4* wp = (const float4*)conv_w;
#pragma unroll
                for (int u = 0; u < 8; ++u) {
                    float4 q = wp[c0 + u];
                    wt[u][0]=q.x; wt[u][1]=q.y; wt[u][2]=q.z; wt[u][3]=q.w;
                }
                float4 b0 = ((const float4*)conv_b)[seg * 2];
                float4 b1 = ((const float4*)conv_b)[seg * 2 + 1];
                bias[0]=b0.x; bias[1]=b0.y; bias[2]=b0.z; bias[3]=b0.w;
                bias[4]=b1.x; bias[5]=b1.y; bias[6]=b1.z; bias[7]=b1.w;
            } else {
                const bhalf8* wp = (const bhalf8*)conv_w;
#pragma unroll
                for (int u = 0; u < 4; ++u) {
                    bhalf8 q = wp[seg * 4 + u];
#pragma unroll
                    for (int t4 = 0; t4 < 4; ++t4) {
                        wt[2*u][t4]   = s2f(q[t4]);
                        wt[2*u+1][t4] = s2f(q[4 + t4]);
                    }
                }
                bhalf8 bq = ((const bhalf8*)conv_b)[seg];
#pragma unroll
                for (int j = 0; j < 8; ++j) bias[j] = s2f(bq[j]);
            }
#pragma unroll
            for (int r = 0; r < 8; ++r) {
                bhalf8 i0 = *(const bhalf8*)&smem[(r + 0) * CONV_DIM + c0];
                bhalf8 i1 = *(const bhalf8*)&smem[(r + 1) * CONV_DIM + c0];
                bhalf8 i2 = *(const bhalf8*)&smem[(r + 2) * CONV_DIM + c0];
                bhalf8 i3 = *(const bhalf8*)&smem[(r + 3) * CONV_DIM + c0];
                bhalf8 out;
#pragma unroll
                for (int j = 0; j < 8; ++j) {
                    float acc = bias[j];
                    acc = fmaf(s2f(i0[j]), wt[j][0], acc);
                    acc = fmaf(s2f(i1[j]), wt[j][1], acc);
                    acc = fmaf(s2f(i2[j]), wt[j][2], acc);
                    acc = fmaf(s2f(i3[j]), wt[j][3], acc);
                    out[j] = f2bs(acc / (1.f + expf(-acc)));
                }
                const int row = r0 + r;
                if (c0 < 2048)
                    *(bhalf8*)&xs_bf[(size_t)row * 2048 + c0] = out;
                else if (c0 < 2176)
                    *(bhalf8*)&B_bf[(size_t)row * 128 + (c0 - 2048)] = out;
                else
                    *(bhalf8*)&C_bf[(size_t)row * 128 + (c0 - 2176)] = out;
            }
        }
    } else {
        float* xsh = (float*)smem;
        const int r0 = (blockIdx.x - 256) * 8;
        if (isf) {
            const float4* xp = (const float4*)xraw;
            for (int i4 = threadIdx.x; i4 < 2048; i4 += 256)
                *(float4*)&xsh[i4 * 4] = xp[(size_t)r0 * 256 + i4];
        } else {
            const bhalf8* xp = (const bhalf8*)xraw;
            for (int i8 = threadIdx.x; i8 < 1024; i8 += 256) {
                bhalf8 v = xp[(size_t)r0 * 128 + i8];
#pragma unroll
                for (int q = 0; q < 8; ++q) xsh[i8 * 8 + q] = s2f(v[q]);
            }
        }
        __syncthreads();
        const int h = threadIdx.x >> 3;
        const int t = threadIdx.x & 7;
        const size_t wb = (size_t)(4352 + h) * D_MODEL;
        float s[8];
#pragma unroll
        for (int r = 0; r < 8; ++r) s[r] = 0.f;
        if (isf) {
            const float4* wp = (const float4*)wraw;
            for (int k0 = 0; k0 < D_MODEL; k0 += 32) {
                float4 w4 = wp[(wb + k0) / 4 + t];
#pragma unroll
                for (int r = 0; r < 8; ++r) {
                    float4 x4 = *(const float4*)&xsh[r * D_MODEL + k0 + t * 4];
                    s[r] = fmaf(w4.x, x4.x, fmaf(w4.y, x4.y,
                           fmaf(w4.z, x4.z, fmaf(w4.w, x4.w, s[r]))));
                }
            }
        } else {
            const __hip_bfloat16* wp = (const __hip_bfloat16*)wraw;
            for (int k0 = 0; k0 < D_MODEL; k0 += 64) {
                bhalf8 w8 = *(const bhalf8*)&wp[wb + k0 + t * 8];
#pragma unroll
                for (int r = 0; r < 8; ++r) {
                    float4 xa = *(const float4*)&xsh[r * D_MODEL + k0 + t * 8];
                    float4 xb = *(const float4*)&xsh[r * D_MODEL + k0 + t * 8 + 4];
                    s[r] = fmaf(s2f(w8[0]), xa.x, fmaf(s2f(w8[1]), xa.y,
                           fmaf(s2f(w8[2]), xa.z, fmaf(s2f(w8[3]), xa.w, s[r]))));
                    s[r] = fmaf(s2f(w8[4]), xb.x, fmaf(s2f(w8[5]), xb.y,
                           fmaf(s2f(w8[6]), xb.z, fmaf(s2f(w8[7]), xb.w, s[r]))));
                }
            }
        }
#pragma unroll
        for (int r = 0; r < 8; ++r) {
            s[r] += __shfl_xor(s[r], 1);
            s[r] += __shfl_xor(s[r], 2);
            s[r] += __shfl_xor(s[r], 4);
        }
        if (t == 0) {
            float bias = rdin(dt_bias, h, isf);
#pragma unroll
            for (int r = 0; r < 8; ++r) {
                float raw = s[r] + bias;
                dtp[(size_t)(r0 + r) * NHEADS + h] = raw > 20.f ? raw : log1pf(expf(raw));
            }
        }
    }
}

// ---------------------------------------------------------------------------
// FUSED COOPERATIVE SCAN (launched only if occupancy gate passes).
// Reader-side __threadfence() after each grid sync = agent-scope acquire
// (invalidates stale L1/L2 lines before consuming other blocks' writes).
// __launch_bounds__(256,4): VGPR <= 128, 4 blocks/CU => 1024 co-resident.
// ---------------------------------------------------------------------------
__global__ __launch_bounds__(256, 4)
void scan_fused(const __hip_bfloat16* __restrict__ xs_bf,
                const __hip_bfloat16* __restrict__ B_bf,
                const __hip_bfloat16* __restrict__ C_bf,
                const float* __restrict__ dtp, const void* __restrict__ Alog,
                const int* __restrict__ flagp,
                float* __restrict__ decayg,
                __hip_bfloat16* __restrict__ Sb,
                __hip_bfloat16* __restrict__ hst,
                const __hip_bfloat16* __restrict__ zxb,
                const void* __restrict__ Draw,
                __hip_bfloat16* __restrict__ vbuf,
                float* __restrict__ rowsum)
{
    __shared__ short Xt[64 * XT_STR];
    __shared__ short BtU[128 * XT_STR];
    __shared__ float cumS[Q], uS[Q], dtS[Q];
    const int bhc = blockIdx.x;
    const int c = bhc & 15, h = (bhc >> 4) & 31, b = bhc >> 9;
    const int row0 = b * SEQLEN + c * Q;
    const int isf = *flagp;
    const int wave = threadIdx.x >> 6, lane = threadIdx.x & 63;
    const int lr = lane & 15, lq = lane >> 4;

    if (threadIdx.x < 2) rowsum[bhc * 2 + threadIdx.x] = 0.f;

    if (threadIdx.x < 64) {
        const int t = threadIdx.x;
        const float An = -expf(rdin(Alog, h, isf));
        const float dt = dtp[(size_t)(row0 + t) * NHEADS + h];
        float cum = dt * An;
#pragma unroll
        for (int ofs = 1; ofs < 64; ofs <<= 1) {
            float v = __shfl_up(cum, ofs);
            if (t >= ofs) cum += v;
        }
        float tot = __shfl(cum, 63);
        cumS[t] = cum; dtS[t] = dt;
        uS[t] = expf(tot - cum) * dt;
        if (t == 63) decayg[bhc] = expf(tot);
    }
    __syncthreads();

#pragma unroll
    for (int i = 0; i < 2; ++i) {
        int seg = threadIdx.x + i * 256;
        int t = seg >> 3, p8 = (seg & 7) * 8;
        bhalf8 v = *(const bhalf8*)&xs_bf[(size_t)(row0 + t) * 2048 + h * 64 + p8];
#pragma unroll
        for (int j = 0; j < 8; ++j)
            Xt[(p8 + j) * XT_STR + t] = v[j];
    }
#pragma unroll
    for (int i = 0; i < 4; ++i) {
        int seg = threadIdx.x + i * 256;
        int t = seg >> 4, n8 = (seg & 15) * 8;
        float ut = uS[t];
        bhalf8 v = *(const bhalf8*)&B_bf[(size_t)(row0 + t) * 128 + n8];
#pragma unroll
        for (int j = 0; j < 8; ++j)
            BtU[(n8 + j) * XT_STR + t] = f2bs(s2f(v[j]) * ut);
    }
    __syncthreads();

    // S[p,n] = sum_t x_t[p] * (u_t B_t[n]) -> Sb (bf16)
    {
        const int p0 = wave * 16;
        f32x4 acc[8];
#pragma unroll
        for (int j = 0; j < 8; ++j) acc[j] = (f32x4){0.f,0.f,0.f,0.f};
#pragma unroll
        for (int kk = 0; kk < 64; kk += 32) {
            bhalf8 af = *(const bhalf8*)&Xt[(p0 + lr) * XT_STR + kk + lq * 8];
#pragma unroll
            for (int j = 0; j < 8; ++j) {
                bhalf8 bf = *(const bhalf8*)&BtU[(j * 16 + lr) * XT_STR + kk + lq * 8];
                acc[j] = __builtin_amdgcn_mfma_f32_16x16x32_bf16(af, bf, acc[j], 0, 0, 0);
            }
        }
#pragma unroll
        for (int j = 0; j < 8; ++j)
#pragma unroll
            for (int r = 0; r < 4; ++r) {
                int p = p0 + lq * 4 + r;
                int n = j * 16 + lr;
                Sb[(size_t)bhc * 8192 + p * 128 + n] = __float2bfloat16(acc[j][r]);
            }
    }
    __threadfence();               // release Sb/decayg writes
    cg::this_grid().sync();
    __threadfence();               // acquire: invalidate stale lines

    // inter-chunk recurrence (2 elems/thread over 1024 blocks)
    {
        const int bh = blockIdx.x >> 4;
        const int sl = blockIdx.x & 15;
        const int off = sl * 512 + threadIdx.x * 2;
        float h0 = 0.f, h1 = 0.f;
        for (int cc = 0; cc < NCHUNK; ++cc) {
            size_t base = ((size_t)bh * NCHUNK + cc) * 8192 + off;
            short2v hb;
            hb[0] = f2bs(h0); hb[1] = f2bs(h1);
            *(short2v*)&hst[base] = hb;
            short2v sv = *(const short2v*)&Sb[base];
            float d = decayg[bh * NCHUNK + cc];
            h0 = fmaf(h0, d, s2f(sv[0]));
            h1 = fmaf(h1, d, s2f(sv[1]));
        }
    }
    __threadfence();               // release hst writes
    cg::this_grid().sync();
    __threadfence();               // acquire

    // GM (LDS) + M.X + C.hst + gating
    short* zS = BtU;
    short* Mt = BtU + 64 * XT_STR;
    const float Dh = rdin(Draw, h, isf);

#pragma unroll
    for (int i = 0; i < 2; ++i) {
        int seg = threadIdx.x + i * 256;
        int t = seg >> 3, p8 = (seg & 7) * 8;
        bhalf8 zv = *(const bhalf8*)&zxb[(size_t)(row0 + t) * ZX_STR + h * 64 + p8];
        *(bhalf8*)&zS[t * XT_STR + p8] = zv;
    }

    const int t0 = wave * 16;
    {
        f32x4 accg[4];
#pragma unroll
        for (int j = 0; j < 4; ++j) accg[j] = (f32x4){0.f,0.f,0.f,0.f};
#pragma unroll
        for (int kk = 0; kk < 128; kk += 32) {
            bhalf8 af = *(const bhalf8*)&C_bf[(size_t)(row0 + t0 + lr) * 128 + kk + lq * 8];
#pragma unroll
            for (int j = 0; j < 4; ++j) {
                bhalf8 bf = *(const bhalf8*)&B_bf[(size_t)(row0 + j * 16 + lr) * 128 + kk + lq * 8];
                accg[j] = __builtin_amdgcn_mfma_f32_16x16x32_bf16(af, bf, accg[j], 0, 0, 0);
            }
        }
#pragma unroll
        for (int j = 0; j < 4; ++j)
#pragma unroll
            for (int r = 0; r < 4; ++r) {
                int t = t0 + lq * 4 + r;
                int s = j * 16 + lr;
                float m = (s <= t) ? accg[j][r] * expf(cumS[t] - cumS[s]) * dtS[s] : 0.f;
                Mt[t * XT_STR + s] = f2bs(m);
            }
    }
    __syncthreads();

    f32x4 acc1[4], acc2[4];
#pragma unroll
    for (int j = 0; j < 4; ++j) { acc1[j] = (f32x4){0.f,0.f,0.f,0.f}; acc2[j] = acc1[j]; }
#pragma unroll
    for (int kk = 0; kk < 64; kk += 32) {
        bhalf8 af = *(const bhalf8*)&Mt[(t0 + lr) * XT_STR + kk + lq * 8];
#pragma unroll
        for (int j = 0; j < 4; ++j) {
            bhalf8 bf = *(const bhalf8*)&Xt[(j * 16 + lr) * XT_STR + kk + lq * 8];
            acc1[j] = __builtin_amdgcn_mfma_f32_16x16x32_bf16(af, bf, acc1[j], 0, 0, 0);
        }
    }
#pragma unroll
    for (int kk = 0; kk < 128; kk += 32) {
        bhalf8 af = *(const bhalf8*)&C_bf[(size_t)(row0 + t0 + lr) * 128 + kk + lq * 8];
#pragma unroll
        for (int j = 0; j < 4; ++j) {
            bhalf8 bf = *(const bhalf8*)&hst[(size_t)bhc * 8192 + (j * 16 + lr) * 128 + kk + lq * 8];
            acc2[j] = __builtin_amdgcn_mfma_f32_16x16x32_bf16(af, bf, acc2[j], 0, 0, 0);
        }
    }
    float ex[4];
#pragma unroll
    for (int r = 0; r < 4; ++r) ex[r] = expf(cumS[t0 + lq * 4 + r]);

    float vv[4][4];
    float s2[4] = {0.f, 0.f, 0.f, 0.f};
#pragma unroll
    for (int j = 0; j < 4; ++j)
#pragma unroll
        for (int r = 0; r < 4; ++r) {
            int t = t0 + lq * 4 + r;
            int p = j * 16 + lr;
            float xv = s2f(Xt[p * XT_STR + t]);
            float y = acc1[j][r] + ex[r] * acc2[j][r] + Dh * xv;
            float zz = s2f(zS[t * XT_STR + p]);
            float v = y * (zz / (1.f + expf(-zz)));
            vv[j][r] = v;
            s2[r] += v * v;
        }
#pragma unroll
    for (int r = 0; r < 4; ++r) {
        s2[r] += __shfl_xor(s2[r], 1);
        s2[r] += __shfl_xor(s2[r], 2);
        s2[r] += __shfl_xor(s2[r], 4);
        s2[r] += __shfl_xor(s2[r], 8);
    }
    if (lr == 0)
#pragma unroll
        for (int r = 0; r < 4; ++r)
            atomicAdd(&rowsum[row0 + t0 + lq * 4 + r], s2[r]);

    __syncthreads();
#pragma unroll
    for (int j = 0; j < 4; ++j)
#pragma unroll
        for (int r = 0; r < 4; ++r)
            zS[(t0 + lq * 4 + r) * XT_STR + j * 16 + lr] = f2bs(vv[j][r]);
    __syncthreads();
#pragma unroll
    for (int i = 0; i < 2; ++i) {
        int seg = threadIdx.x + i * 256;
        int t = seg >> 3, p8 = (seg & 7) * 8;
        bhalf8 o = *(const bhalf8*)&zS[t * XT_STR + p8];
        *(bhalf8*)&vbuf[(size_t)(row0 + t) * D_INNER + h * 64 + p8] = o;
    }
}

// ---------------------------------------------------------------------------
// FALLBACK TRIO (round-9 versions, known-good) — used if occupancy gate fails.
// ---------------------------------------------------------------------------
__global__ __launch_bounds__(256)
void chunk_kernel(const __hip_bfloat16* __restrict__ xs_bf,
                  const __hip_bfloat16* __restrict__ B_bf,
                  const float* __restrict__ dtp, const void* __restrict__ Alog,
                  const int* __restrict__ flagp,
                  float* __restrict__ cumg, float* __restrict__ decayg,
                  __hip_bfloat16* __restrict__ Sb,
                  float* __restrict__ rowsum)
{
    __shared__ float cumS[Q], uS[Q];
    __shared__ short Xt[64 * XT_STR];
    __shared__ short Bt[128 * XT_STR];
    const int bhc = blockIdx.x;
    const int c = bhc & 15, h = (bhc >> 4) & 31, b = bhc >> 9;
    const int row0 = b * SEQLEN + c * Q;
    const int isf = *flagp;

    if (threadIdx.x < 2) rowsum[bhc * 2 + threadIdx.x] = 0.f;
    if (threadIdx.x < 64) {
        const int t = threadIdx.x;
        const float An = -expf(rdin(Alog, h, isf));
        const float dt = dtp[(size_t)(row0 + t) * NHEADS + h];
        float cum = dt * An;
#pragma unroll
        for (int ofs = 1; ofs < 64; ofs <<= 1) {
            float v = __shfl_up(cum, ofs);
            if (t >= ofs) cum += v;
        }
        float tot = __shfl(cum, 63);
        cumS[t] = cum;
        uS[t] = expf(tot - cum) * dt;
        cumg[(size_t)bhc * Q + t] = cum;
        if (t == 63) decayg[bhc] = expf(tot);
    }
    __syncthreads();

#pragma unroll
    for (int i = 0; i < 2; ++i) {
        int seg = threadIdx.x + i * 256;
        int t = seg >> 3, p8 = (seg & 7) * 8;
        float ut = uS[t];
        bhalf8 v = *(const bhalf8*)&xs_bf[(size_t)(row0 + t) * 2048 + h * 64 + p8];
#pragma unroll
        for (int j = 0; j < 8; ++j)
            Xt[(p8 + j) * XT_STR + t] = f2bs(s2f(v[j]) * ut);
    }
#pragma unroll
    for (int i = 0; i < 4; ++i) {
        int seg = threadIdx.x + i * 256;
        int t = seg >> 4, n8 = (seg & 15) * 8;
        bhalf8 v = *(const bhalf8*)&B_bf[(size_t)(row0 + t) * 128 + n8];
#pragma unroll
        for (int j = 0; j < 8; ++j)
            Bt[(n8 + j) * XT_STR + t] = v[j];
    }
    __syncthreads();

    const int wave = threadIdx.x >> 6, lane = threadIdx.x & 63;
    const int lr = lane & 15, lq = lane >> 4;
    const int p0 = wave * 16;
    f32x4 acc[8];
#pragma unroll
    for (int j = 0; j < 8; ++j) acc[j] = (f32x4){0.f,0.f,0.f,0.f};
#pragma unroll
    for (int kk = 0; kk < 64; kk += 32) {
        bhalf8 af = *(const bhalf8*)&Xt[(p0 + lr) * XT_STR + kk + lq * 8];
#pragma unroll
        for (int j = 0; j < 8; ++j) {
            bhalf8 bf = *(const bhalf8*)&Bt[(j * 16 + lr) * XT_STR + kk + lq * 8];
            acc[j] = __builtin_amdgcn_mfma_f32_16x16x32_bf16(af, bf, acc[j], 0, 0, 0);
        }
    }
#pragma unroll
    for (int j = 0; j < 8; ++j)
#pragma unroll
        for (int r = 0; r < 4; ++r) {
            int p = p0 + lq * 4 + r;
            int n = j * 16 + lr;
            Sb[(size_t)bhc * 8192 + p * 128 + n] = __float2bfloat16(acc[j][r]);
        }
}

__global__ __launch_bounds__(256)
void rec_kernel(const __hip_bfloat16* __restrict__ Sb,
                const float* __restrict__ decayg,
                __hip_bfloat16* __restrict__ hst)
{
    const int bh = blockIdx.x >> 3;
    const int sl = blockIdx.x & 7;
    const int off = sl * 1024 + threadIdx.x * 4;
    float h0 = 0.f, h1 = 0.f, h2 = 0.f, h3 = 0.f;
    for (int c = 0; c < NCHUNK; ++c) {
        size_t base = ((size_t)bh * NCHUNK + c) * 8192 + off;
        short4v hb;
        hb[0] = f2bs(h0); hb[1] = f2bs(h1); hb[2] = f2bs(h2); hb[3] = f2bs(h3);
        *(short4v*)&hst[base] = hb;
        short4v sv = *(const short4v*)&Sb[base];
        float d = decayg[bh * NCHUNK + c];
        h0 = fmaf(h0, d, s2f(sv[0])); h1 = fmaf(h1, d, s2f(sv[1]));
        h2 = fmaf(h2, d, s2f(sv[2])); h3 = fmaf(h3, d, s2f(sv[3]));
    }
}

__global__ __launch_bounds__(256)
void y_kernel(const __hip_bfloat16* __restrict__ xs_bf,
              const __hip_bfloat16* __restrict__ B_bf,
              const __hip_bfloat16* __restrict__ C_bf,
              const __hip_bfloat16* __restrict__ hst,
              const float* __restrict__ cumg,
              const float* __restrict__ dtp,
              const __hip_bfloat16* __restrict__ zxb,
              const void* __restrict__ Draw, const int* __restrict__ flagp,
              __hip_bfloat16* __restrict__ vbuf, float* __restrict__ rowsum)
{
    __shared__ short Xt[64 * XT_STR];
    __shared__ short zS[64 * XT_STR];
    __shared__ short Mt[64 * XT_STR];
    __shared__ float cumS[Q], dtS[Q];
    const int bhc = blockIdx.x;
    const int c = bhc & 15, h = (bhc >> 4) & 31, b = bhc >> 9;
    const int row0 = b * SEQLEN + c * Q;
    const int isf = *flagp;
    const float Dh = rdin(Draw, h, isf);

    if (threadIdx.x < 64) {
        cumS[threadIdx.x] = cumg[(size_t)bhc * Q + threadIdx.x];
        dtS[threadIdx.x]  = dtp[(size_t)(row0 + threadIdx.x) * NHEADS + h];
    }
#pragma unroll
    for (int i = 0; i < 2; ++i) {
        int seg = threadIdx.x + i * 256;
        int t = seg >> 3, p8 = (seg & 7) * 8;
        bhalf8 v = *(const bhalf8*)&xs_bf[(size_t)(row0 + t) * 2048 + h * 64 + p8];
#pragma unroll
        for (int j = 0; j < 8; ++j)
            Xt[(p8 + j) * XT_STR + t] = v[j];
        bhalf8 zv = *(const bhalf8*)&zxb[(size_t)(row0 + t) * ZX_STR + h * 64 + p8];
        *(bhalf8*)&zS[t * XT_STR + p8] = zv;
    }
    __syncthreads();

    const int wave = threadIdx.x >> 6, lane = threadIdx.x & 63;
    const int lr = lane & 15, lq = lane >> 4;
    const int t0 = wave * 16;

    {
        f32x4 accg[4];
#pragma unroll
        for (int j = 0; j < 4; ++j) accg[j] = (f32x4){0.f,0.f,0.f,0.f};
#pragma unroll
        for (int kk = 0; kk < 128; kk += 32) {
            bhalf8 af = *(const bhalf8*)&C_bf[(size_t)(row0 + t0 + lr) * 128 + kk + lq * 8];
#pragma unroll
            for (int j = 0; j < 4; ++j) {
                bhalf8 bf = *(const bhalf8*)&B_bf[(size_t)(row0 + j * 16 + lr) * 128 + kk + lq * 8];
                accg[j] = __builtin_amdgcn_mfma_f32_16x16x32_bf16(af, bf, accg[j], 0, 0, 0);
            }
        }
#pragma unroll
        for (int j = 0; j < 4; ++j)
#pragma unroll
            for (int r = 0; r < 4; ++r) {
                int t = t0 + lq * 4 + r;
                int s = j * 16 + lr;
                float m = (s <= t) ? accg[j][r] * expf(cumS[t] - cumS[s]) * dtS[s] : 0.f;
                Mt[t * XT_STR + s] = f2bs(m);
            }
    }
    __syncthreads();

    f32x4 acc1[4], acc2[4];
#pragma unroll
    for (int j = 0; j < 4; ++j) { acc1[j] = (f32x4){0.f,0.f,0.f,0.f}; acc2[j] = acc1[j]; }
#pragma unroll
    for (int kk = 0; kk < 64; kk += 32) {
        bhalf8 af = *(const bhalf8*)&Mt[(t0 + lr) * XT_STR + kk + lq * 8];
#pragma unroll
        for (int j = 0; j < 4; ++j) {
            bhalf8 bf = *(const bhalf8*)&Xt[(j * 16 + lr) * XT_STR + kk + lq * 8];
            acc1[j] = __builtin_amdgcn_mfma_f32_16x16x32_bf16(af, bf, acc1[j], 0, 0, 0);
        }
    }
#pragma unroll
    for (int kk = 0; kk < 128; kk += 32) {
        bhalf8 af = *(const bhalf8*)&C_bf[(size_t)(row0 + t0 + lr) * 128 + kk + lq * 8];
#pragma unroll
        for (int j = 0; j < 4; ++j) {
            bhalf8 bf = *(const bhalf8*)&hst[(size_t)bhc * 8192 + (j * 16 + lr) * 128 + kk + lq * 8];
            acc2[j] = __builtin_amdgcn_mfma_f32_16x16x32_bf16(af, bf, acc2[j], 0, 0, 0);
        }
    }
    float ex[4];
#pragma unroll
    for (int r = 0; r < 4; ++r) ex[r] = expf(cumS[t0 + lq * 4 + r]);

    float vv[4][4];
    float s2[4] = {0.f, 0.f, 0.f, 0.f};
#pragma unroll
    for (int j = 0; j < 4; ++j)
#pragma unroll
        for (int r = 0; r < 4; ++r) {
            int t = t0 + lq * 4 + r;
            int p = j * 16 + lr;
            float xv = s2f(Xt[p * XT_STR + t]);
            float y = acc1[j][r] + ex[r] * acc2[j][r] + Dh * xv;
            float zz = s2f(zS[t * XT_STR + p]);
            float v = y * (zz / (1.f + expf(-zz)));
            vv[j][r] = v;
            s2[r] += v * v;
        }
#pragma unroll
    for (int r = 0; r < 4; ++r) {
        s2[r] += __shfl_xor(s2[r], 1);
        s2[r] += __shfl_xor(s2[r], 2);
        s2[r] += __shfl_xor(s2[r], 4);
        s2[r] += __shfl_xor(s2[r], 8);
    }
    if (lr == 0)
#pragma unroll
        for (int r = 0; r < 4; ++r)
            atomicAdd(&rowsum[row0 + t0 + lq * 4 + r], s2[r]);

    __syncthreads();
#pragma unroll
    for (int j = 0; j < 4; ++j)
#pragma unroll
        for (int r = 0; r < 4; ++r)
            zS[(t0 + lq * 4 + r) * XT_STR + j * 16 + lr] = f2bs(vv[j][r]);
    __syncthreads();
#pragma unroll
    for (int i = 0; i < 2; ++i) {
        int seg = threadIdx.x + i * 256;
        int t = seg >> 3, p8 = (seg & 7) * 8;
        bhalf8 o = *(const bhalf8*)&zS[t * XT_STR + p8];
        *(bhalf8*)&vbuf[(size_t)(row0 + t) * D_INNER + h * 64 + p8] = o;
    }
}

extern "C" void kernel_launch(void* const* d_in, const int* in_sizes, int n_in,
                              void* d_out, int out_size, void* d_ws, size_t ws_size,
                              hipStream_t stream)
{
    const void* x_raw    = d_in[0];
    const void* inw_raw  = d_in[1];
    const void* convw    = d_in[2];
    const void* convb    = d_in[3];
    const void* dtb      = d_in[4];
    const void* Alog     = d_in[5];
    const void* Dsk      = d_in[6];
    const void* normw    = d_in[7];
    const void* outw_raw = d_in[8];

    char* ws = (char*)d_ws;
    size_t off = 0;
    int* flag = (int*)(ws + off);                      off += 256;
    float* rowsum = (float*)(ws + off);                off += (size_t)NROWS * 4;
    __hip_bfloat16* xb    = (__hip_bfloat16*)(ws+off); off += (size_t)NROWS * D_MODEL * 2;
    __hip_bfloat16* inwb  = (__hip_bfloat16*)(ws+off); off += (size_t)4384 * D_MODEL * 2;
    __hip_bfloat16* outwb = (__hip_bfloat16*)(ws+off); off += (size_t)D_MODEL * D_INNER * 2;
    __hip_bfloat16* zxb   = (__hip_bfloat16*)(ws+off); off += (size_t)NROWS * ZX_STR * 2;
    __hip_bfloat16* xs_bf = (__hip_bfloat16*)(ws+off); off += (size_t)NROWS * 2048 * 2;
    __hip_bfloat16* B_bf  = (__hip_bfloat16*)(ws+off); off += (size_t)NROWS * 128 * 2;
    __hip_bfloat16* C_bf  = (__hip_bfloat16*)(ws+off); off += (size_t)NROWS * 128 * 2;
    float* dtp   = (float*)(ws+off);                   off += (size_t)NROWS * NHEADS * 4;
    float* cumg  = (float*)(ws+off);                   off += (size_t)1024 * Q * 4;
    float* decayg= (float*)(ws+off);                   off += (size_t)1024 * 4;
    __hip_bfloat16* hst   = (__hip_bfloat16*)(ws+off); off += (size_t)1024 * 8192 * 2;
    __hip_bfloat16* Sb    = (__hip_bfloat16*)(ws+off); off += (size_t)1024 * 8192 * 2;
    __hip_bfloat16* vbuf = Sb;   // Sb dead before vbuf written (both paths)

    to_bf16_all<<<(XN8+WN8+ON8)/256, 256, 0, stream>>>(x_raw, inw_raw, outw_raw,
                                                       normw, xb, inwb, outwb, flag);
    gemm_bt<0,64,128,1,4><<<dim3(34, 32), 256, 0, stream>>>(
        xb, inwb, zxb, nullptr, nullptr, nullptr, flag, D_MODEL, ZX_STR);
    convdt<<<512, 256, 0, stream>>>(zxb, convw, convb, x_raw, inw_raw, dtb, flag,
                                    xs_bf, B_bf, C_bf, dtp);

    // Occupancy gate: cooperative path needs all 1024 blocks co-resident
    // (256 CUs x >=4 blocks/CU). Pure host query — capture-safe, deterministic.
    int maxb = 0;
    hipError_t qe = hipOccupancyMaxActiveBlocksPerMultiprocessor(&maxb, scan_fused, 256, 0);
    if (qe == hipSuccess && maxb >= 4) {
        void* args[] = {
            (void*)&xs_bf, (void*)&B_bf, (void*)&C_bf, (void*)&dtp,
            (void*)&Alog, (void*)&flag, (void*)&decayg, (void*)&Sb,
            (void*)&hst, (void*)&zxb, (void*)&Dsk, (void*)&vbuf, (void*)&rowsum
        };
        hipLaunchCooperativeKernel((void*)scan_fused, dim3(1024), dim3(256),
                                   args, 0, stream);
    } else {
        chunk_kernel<<<1024, 256, 0, stream>>>(xs_bf, B_bf, dtp, Alog, flag,
                                               cumg, decayg, Sb, rowsum);
        rec_kernel<<<512, 256, 0, stream>>>(Sb, decayg, hst);
        y_kernel<<<1024, 256, 0, stream>>>(xs_bf, B_bf, C_bf, hst, cumg, dtp, zxb,
                                           Dsk, flag, vbuf, rowsum);
    }

    gemm_bt<1,64,64,2,2><<<dim3(16, 32), 256, 0, stream>>>(
        vbuf, outwb, nullptr, x_raw, d_out, rowsum, flag, D_INNER, D_MODEL);
}

// Round 12
// 222.776 us; speedup vs baseline: 1.0170x; 1.0170x over previous
//
#include <hip/hip_runtime.h>
#include <hip/hip_bf16.h>
#include <math.h>

#define NHEADS   32
#define CONV_DIM 2304
#define D_INNER  2048
#define SEQLEN   1024
#define NROWS    2048     // BATCH*SEQLEN
#define ZX_STR   4352     // z(2048) + xBC(2304); dt columns handled separately
#define D_MODEL  1024
#define Q        64       // chunk length
#define NCHUNK   16       // SEQLEN / Q
#define XT_STR   72       // LDS transpose row stride (shorts)

typedef __attribute__((ext_vector_type(8))) short bhalf8;
typedef __attribute__((ext_vector_type(8))) short short8;
typedef __attribute__((ext_vector_type(4))) short short4v;
typedef __attribute__((ext_vector_type(4))) float f32x4;

__device__ __forceinline__ float bf2f(__hip_bfloat16 v){ return __bfloat162float(v); }
__device__ __forceinline__ short f2bs(float f){ __hip_bfloat16 h = __float2bfloat16(f); return *(short*)&h; }
__device__ __forceinline__ float s2f(short s){ __hip_bfloat16 h = *(__hip_bfloat16*)&s; return __bfloat162float(h); }
__device__ __forceinline__ float rdin(const void* p, size_t i, int isf){
    return isf ? ((const float*)p)[i] : __bfloat162float(((const __hip_bfloat16*)p)[i]);
}
// transpose-tile column swizzle: column t lives at block (t>>3)^((row>>3)&7)
__device__ __forceinline__ int tsw(int row, int t){
    return ((((t >> 3) ^ ((row >> 3) & 7)) << 3) | (t & 7));
}

// ---------------------------------------------------------------------------
// Fused normalize pass with INLINE dtype vote.
// If inputs are bf16 (isf==0): x / in_proj_w copies SKIPPED (gemm reads raw).
// out_proj_w always rebuilt with norm_w folded in.
// ---------------------------------------------------------------------------
#define XN8 262144   // 2048*1024/8
#define WN8 561152   // 4384*1024/8
#define ON8 262144   // 1024*2048/8
__global__ __launch_bounds__(256)
void to_bf16_all(const void* __restrict__ xs, const void* __restrict__ ws,
                 const void* __restrict__ os, const void* __restrict__ normw,
                 __hip_bfloat16* __restrict__ xd, __hip_bfloat16* __restrict__ wd,
                 __hip_bfloat16* __restrict__ od, int* __restrict__ flagp)
{
    const unsigned short* xu = (const unsigned short*)xs;
    int cnt = 0;
    for (int k = threadIdx.x; k < 4096; k += 256) {
        int e = (xu[2 * k] >> 7) & 0xFF;
        cnt += (e >= 90 && e <= 141) ? 1 : 0;
    }
#pragma unroll
    for (int m = 1; m < 64; m <<= 1) cnt += __shfl_xor(cnt, m);
    __shared__ int red[4];
    if ((threadIdx.x & 63) == 0) red[threadIdx.x >> 6] = cnt;
    __syncthreads();
    const int isf = ((red[0] + red[1] + red[2] + red[3]) < 2048) ? 1 : 0;
    if (blockIdx.x == 0 && threadIdx.x == 0) *flagp = isf;

    int i = blockIdx.x * 256 + threadIdx.x;
    if (i < XN8 + WN8) {
        if (!isf) return;                      // bf16 inputs: no copy needed
        const void* src; __hip_bfloat16* dst; int j;
        if (i < XN8) { src = xs; dst = xd; j = i; }
        else         { src = ws; dst = wd; j = i - XN8; }
        const float4* s = (const float4*)src;
        float4 a = s[2 * j], b = s[2 * j + 1];
        short8 r;
        r[0]=f2bs(a.x); r[1]=f2bs(a.y); r[2]=f2bs(a.z); r[3]=f2bs(a.w);
        r[4]=f2bs(b.x); r[5]=f2bs(b.y); r[6]=f2bs(b.z); r[7]=f2bs(b.w);
        ((short8*)dst)[j] = r;
    } else {
        int j = i - XN8 - WN8;
        int k0 = (j * 8) & (D_INNER - 1);
        float v[8];
        if (isf) {
            const float4* s = (const float4*)os;
            float4 a = s[2 * j], b = s[2 * j + 1];
            v[0]=a.x; v[1]=a.y; v[2]=a.z; v[3]=a.w;
            v[4]=b.x; v[5]=b.y; v[6]=b.z; v[7]=b.w;
        } else {
            bhalf8 a = ((const bhalf8*)os)[j];
#pragma unroll
            for (int q = 0; q < 8; ++q) v[q] = s2f(a[q]);
        }
        short8 r;
#pragma unroll
        for (int q = 0; q < 8; ++q)
            r[q] = f2bs(v[q] * rdin(normw, k0 + q, isf));
        ((short8*)od)[j] = r;
    }
}

// ---------------------------------------------------------------------------
// GEMM C[m,n] = sum_k A[m,k]*W[n,k]. XOR-swizzled LDS (16B segments).
// A/W: if raw pointers given and inputs are bf16, reads raw directly (skips
// the canonical copy). MODE 0: bf16 store. MODE 1: RMS scale + residual.
// ---------------------------------------------------------------------------
template<int MODE, int MT, int NT, int WROWS, int WCOLS>
__global__ __launch_bounds__(256)
void gemm_bt(const __hip_bfloat16* __restrict__ Acan, const void* __restrict__ Araw,
             const __hip_bfloat16* __restrict__ Wcan, const void* __restrict__ Wraw,
             __hip_bfloat16* __restrict__ Cb,
             const void* __restrict__ xraw,
             void* __restrict__ outv,
             const float* __restrict__ rowsum,
             const int* __restrict__ flagp,
             int K, int N)
{
    constexpr int FM = MT / WROWS / 16;
    constexpr int FN = NT / WCOLS / 16;
    constexpr int AI = MT / 32;
    constexpr int BI = NT / 32;
    __shared__ short As[MT * 64];
    __shared__ short Bs[NT * 64];
    const int isf = *flagp;
    const __hip_bfloat16* A = (Araw != nullptr && !isf) ? (const __hip_bfloat16*)Araw : Acan;
    const __hip_bfloat16* W = (Wraw != nullptr && !isf) ? (const __hip_bfloat16*)Wraw : Wcan;
    const int m0 = blockIdx.y * MT;
    const int n0 = blockIdx.x * NT;
    const int wave = threadIdx.x >> 6;
    const int lane = threadIdx.x & 63;
    const int lr8 = lane >> 3, lc8 = lane & 7;
    const int lr  = lane & 15, lq  = lane >> 4;
    const int wm = (wave / WCOLS) * (MT / WROWS);
    const int wn = (wave % WCOLS) * (NT / WCOLS);
    const int swl = lr & 7;

    f32x4 acc[FM][FN];
#pragma unroll
    for (int i = 0; i < FM; ++i)
#pragma unroll
        for (int j = 0; j < FN; ++j) acc[i][j] = (f32x4){0.f,0.f,0.f,0.f};

    for (int k0 = 0; k0 < K; k0 += 64) {
#pragma unroll
        for (int i = 0; i < AI; ++i) {
            const int rt = (wave * AI + i) * 8;
            const __hip_bfloat16* gp = A + (size_t)(m0 + rt + lr8) * K + k0 + ((lc8 ^ lr8) << 3);
            __builtin_amdgcn_global_load_lds(
                (const __attribute__((address_space(1))) void*)gp,
                (__attribute__((address_space(3))) void*)&As[rt * 64], 16, 0, 0);
        }
#pragma unroll
        for (int i = 0; i < BI; ++i) {
            const int rt = (wave * BI + i) * 8;
            const __hip_bfloat16* gp = W + (size_t)(n0 + rt + lr8) * K + k0 + ((lc8 ^ lr8) << 3);
            __builtin_amdgcn_global_load_lds(
                (const __attribute__((address_space(1))) void*)gp,
                (__attribute__((address_space(3))) void*)&Bs[rt * 64], 16, 0, 0);
        }
        __syncthreads();
#pragma unroll
        for (int kk = 0; kk < 64; kk += 32) {
            const int sw = (((kk >> 3) + lq) ^ swl) << 3;
            bhalf8 af[FM], bfv[FN];
#pragma unroll
            for (int t = 0; t < FM; ++t)
                af[t]  = *(const bhalf8*)&As[(wm + t * 16 + lr) * 64 + sw];
#pragma unroll
            for (int t = 0; t < FN; ++t)
                bfv[t] = *(const bhalf8*)&Bs[(wn + t * 16 + lr) * 64 + sw];
#pragma unroll
            for (int ti = 0; ti < FM; ++ti)
#pragma unroll
                for (int tj = 0; tj < FN; ++tj)
                    acc[ti][tj] = __builtin_amdgcn_mfma_f32_16x16x32_bf16(
                        af[ti], bfv[tj], acc[ti][tj], 0, 0, 0);
        }
        __syncthreads();
    }

#pragma unroll
    for (int ti = 0; ti < FM; ++ti)
#pragma unroll
        for (int tj = 0; tj < FN; ++tj)
#pragma unroll
            for (int r = 0; r < 4; ++r) {
                int m = m0 + wm + ti * 16 + lq * 4 + r;
                int n = n0 + wn + tj * 16 + lr;
                size_t idx = (size_t)m * N + n;
                float v = acc[ti][tj][r];
                if (MODE == 0) {
                    Cb[idx] = __float2bfloat16(v);
                } else {
                    float scale = rsqrtf(rowsum[m] / (float)D_INNER + 1e-5f);
                    v = v * scale + rdin(xraw, idx, isf);
                    if (isf) ((float*)outv)[idx] = v;
                    else     ((__hip_bfloat16*)outv)[idx] = __float2bfloat16(v);
                }
            }
}

// ---------------------------------------------------------------------------
// MERGED conv+dt kernel, grid 512 (unchanged — known good).
// ---------------------------------------------------------------------------
__global__ __launch_bounds__(256)
void convdt(const __hip_bfloat16* __restrict__ zxb,
            const void* __restrict__ conv_w, const void* __restrict__ conv_b,
            const void* __restrict__ xraw, const void* __restrict__ wraw,
            const void* __restrict__ dt_bias,
            const int* __restrict__ flagp,
            __hip_bfloat16* __restrict__ xs_bf,
            __hip_bfloat16* __restrict__ B_bf,
            __hip_bfloat16* __restrict__ C_bf,
            float* __restrict__ dtp)
{
    __shared__ short smem[11 * CONV_DIM];
    const int isf = *flagp;

    if (blockIdx.x < 256) {
        const int r0 = blockIdx.x * 8;
        const int bstart = r0 & ~(SEQLEN - 1);
        for (int idx = threadIdx.x; idx < 11 * (CONV_DIM / 8); idx += 256) {
            int ii = idx / (CONV_DIM / 8);
            int seg = idx % (CONV_DIM / 8);
            int g = r0 - 3 + ii;
            bhalf8 v;
            if (g >= bstart) {
                v = *(const bhalf8*)&zxb[(size_t)g * ZX_STR + 2048 + seg * 8];
            } else {
#pragma unroll
                for (int j = 0; j < 8; ++j) v[j] = 0;
            }
            *(bhalf8*)&smem[ii * CONV_DIM + seg * 8] = v;
        }
        __syncthreads();

#pragma unroll
        for (int sIt = 0; sIt < 2; ++sIt) {
            const int seg = threadIdx.x + sIt * 256;
            if (seg >= CONV_DIM / 8) break;
            const int c0 = seg * 8;
            float wt[8][4], bias[8];
            if (isf) {
                const float4* wp = (const float4*)conv_w;
#pragma unroll
                for (int u = 0; u < 8; ++u) {
                    float4 q = wp[c0 + u];
                    wt[u][0]=q.x; wt[u][1]=q.y; wt[u][2]=q.z; wt[u][3]=q.w;
                }
                float4 b0 = ((const float4*)conv_b)[seg * 2];
                float4 b1 = ((const float4*)conv_b)[seg * 2 + 1];
                bias[0]=b0.x; bias[1]=b0.y; bias[2]=b0.z; bias[3]=b0.w;
                bias[4]=b1.x; bias[5]=b1.y; bias[6]=b1.z; bias[7]=b1.w;
            } else {
                const bhalf8* wp = (const bhalf8*)conv_w;
#pragma unroll
                for (int u = 0; u < 4; ++u) {
                    bhalf8 q = wp[seg * 4 + u];
#pragma unroll
                    for (int t4 = 0; t4 < 4; ++t4) {
                        wt[2*u][t4]   = s2f(q[t4]);
                        wt[2*u+1][t4] = s2f(q[4 + t4]);
                    }
                }
                bhalf8 bq = ((const bhalf8*)conv_b)[seg];
#pragma unroll
                for (int j = 0; j < 8; ++j) bias[j] = s2f(bq[j]);
            }
#pragma unroll
            for (int r = 0; r < 8; ++r) {
                bhalf8 i0 = *(const bhalf8*)&smem[(r + 0) * CONV_DIM + c0];
                bhalf8 i1 = *(const bhalf8*)&smem[(r + 1) * CONV_DIM + c0];
                bhalf8 i2 = *(const bhalf8*)&smem[(r + 2) * CONV_DIM + c0];
                bhalf8 i3 = *(const bhalf8*)&smem[(r + 3) * CONV_DIM + c0];
                bhalf8 out;
#pragma unroll
                for (int j = 0; j < 8; ++j) {
                    float acc = bias[j];
                    acc = fmaf(s2f(i0[j]), wt[j][0], acc);
                    acc = fmaf(s2f(i1[j]), wt[j][1], acc);
                    acc = fmaf(s2f(i2[j]), wt[j][2], acc);
                    acc = fmaf(s2f(i3[j]), wt[j][3], acc);
                    out[j] = f2bs(acc / (1.f + expf(-acc)));
                }
                const int row = r0 + r;
                if (c0 < 2048)
                    *(bhalf8*)&xs_bf[(size_t)row * 2048 + c0] = out;
                else if (c0 < 2176)
                    *(bhalf8*)&B_bf[(size_t)row * 128 + (c0 - 2048)] = out;
                else
                    *(bhalf8*)&C_bf[(size_t)row * 128 + (c0 - 2176)] = out;
            }
        }
    } else {
        float* xsh = (float*)smem;
        const int r0 = (blockIdx.x - 256) * 8;
        if (isf) {
            const float4* xp = (const float4*)xraw;
            for (int i4 = threadIdx.x; i4 < 2048; i4 += 256)
                *(float4*)&xsh[i4 * 4] = xp[(size_t)r0 * 256 + i4];
        } else {
            const bhalf8* xp = (const bhalf8*)xraw;
            for (int i8 = threadIdx.x; i8 < 1024; i8 += 256) {
                bhalf8 v = xp[(size_t)r0 * 128 + i8];
#pragma unroll
                for (int q = 0; q < 8; ++q) xsh[i8 * 8 + q] = s2f(v[q]);
            }
        }
        __syncthreads();
        const int h = threadIdx.x >> 3;
        const int t = threadIdx.x & 7;
        const size_t wb = (size_t)(4352 + h) * D_MODEL;
        float s[8];
#pragma unroll
        for (int r = 0; r < 8; ++r) s[r] = 0.f;
        if (isf) {
            const float4* wp = (const float4*)wraw;
            for (int k0 = 0; k0 < D_MODEL; k0 += 32) {
                float4 w4 = wp[(wb + k0) / 4 + t];
#pragma unroll
                for (int r = 0; r < 8; ++r) {
                    float4 x4 = *(const float4*)&xsh[r * D_MODEL + k0 + t * 4];
                    s[r] = fmaf(w4.x, x4.x, fmaf(w4.y, x4.y,
                           fmaf(w4.z, x4.z, fmaf(w4.w, x4.w, s[r]))));
                }
            }
        } else {
            const __hip_bfloat16* wp = (const __hip_bfloat16*)wraw;
            for (int k0 = 0; k0 < D_MODEL; k0 += 64) {
                bhalf8 w8 = *(const bhalf8*)&wp[wb + k0 + t * 8];
#pragma unroll
                for (int r = 0; r < 8; ++r) {
                    float4 xa = *(const float4*)&xsh[r * D_MODEL + k0 + t * 8];
                    float4 xb = *(const float4*)&xsh[r * D_MODEL + k0 + t * 8 + 4];
                    s[r] = fmaf(s2f(w8[0]), xa.x, fmaf(s2f(w8[1]), xa.y,
                           fmaf(s2f(w8[2]), xa.z, fmaf(s2f(w8[3]), xa.w, s[r]))));
                    s[r] = fmaf(s2f(w8[4]), xb.x, fmaf(s2f(w8[5]), xb.y,
                           fmaf(s2f(w8[6]), xb.z, fmaf(s2f(w8[7]), xb.w, s[r]))));
                }
            }
        }
#pragma unroll
        for (int r = 0; r < 8; ++r) {
            s[r] += __shfl_xor(s[r], 1);
            s[r] += __shfl_xor(s[r], 2);
            s[r] += __shfl_xor(s[r], 4);
        }
        if (t == 0) {
            float bias = rdin(dt_bias, h, isf);
#pragma unroll
            for (int r = 0; r < 8; ++r) {
                float raw = s[r] + bias;
                dtp[(size_t)(r0 + r) * NHEADS + h] = raw > 20.f ? raw : log1pf(expf(raw));
            }
        }
    }
}

// ---------------------------------------------------------------------------
// Per-(b,h,chunk): [cum scan] + [S: u-scaled X^T·B]. Transpose tiles use the
// tsw() column swizzle — kills the 8-way ds_write_b16 conflicts (5.3M cycles).
// ---------------------------------------------------------------------------
__global__ __launch_bounds__(256)
void chunk_kernel(const __hip_bfloat16* __restrict__ xs_bf,
                  const __hip_bfloat16* __restrict__ B_bf,
                  const float* __restrict__ dtp, const void* __restrict__ Alog,
                  const int* __restrict__ flagp,
                  float* __restrict__ cumg, float* __restrict__ decayg,
                  __hip_bfloat16* __restrict__ Sb,
                  float* __restrict__ rowsum)
{
    __shared__ float cumS[Q], uS[Q];
    __shared__ short Xt[64 * XT_STR];
    __shared__ short Bt[128 * XT_STR];
    const int bhc = blockIdx.x;
    const int c = bhc & 15, h = (bhc >> 4) & 31, b = bhc >> 9;
    const int row0 = b * SEQLEN + c * Q;
    const int isf = *flagp;

    if (threadIdx.x < 2) rowsum[bhc * 2 + threadIdx.x] = 0.f;
    if (threadIdx.x < 64) {
        const int t = threadIdx.x;
        const float An = -expf(rdin(Alog, h, isf));
        const float dt = dtp[(size_t)(row0 + t) * NHEADS + h];
        float cum = dt * An;
#pragma unroll
        for (int ofs = 1; ofs < 64; ofs <<= 1) {
            float v = __shfl_up(cum, ofs);
            if (t >= ofs) cum += v;
        }
        float tot = __shfl(cum, 63);
        cumS[t] = cum;
        uS[t] = expf(tot - cum) * dt;
        cumg[(size_t)bhc * Q + t] = cum;
        if (t == 63) decayg[bhc] = expf(tot);
    }
    __syncthreads();

#pragma unroll
    for (int i = 0; i < 2; ++i) {
        int seg = threadIdx.x + i * 256;
        int t = seg >> 3, p8 = (seg & 7) * 8;
        float ut = uS[t];
        // all 8 rows share row>>3 == seg&7 -> one swizzled column for the seg
        int col = ((((t >> 3) ^ (seg & 7)) << 3) | (t & 7));
        bhalf8 v = *(const bhalf8*)&xs_bf[(size_t)(row0 + t) * 2048 + h * 64 + p8];
#pragma unroll
        for (int j = 0; j < 8; ++j)
            Xt[(p8 + j) * XT_STR + col] = f2bs(s2f(v[j]) * ut);
    }
#pragma unroll
    for (int i = 0; i < 4; ++i) {
        int seg = threadIdx.x + i * 256;
        int t = seg >> 4, n8 = (seg & 15) * 8;
        int col = ((((t >> 3) ^ (seg & 7)) << 3) | (t & 7));   // (n8>>3)&7 == seg&7
        bhalf8 v = *(const bhalf8*)&B_bf[(size_t)(row0 + t) * 128 + n8];
#pragma unroll
        for (int j = 0; j < 8; ++j)
            Bt[(n8 + j) * XT_STR + col] = v[j];
    }
    __syncthreads();

    const int wave = threadIdx.x >> 6, lane = threadIdx.x & 63;
    const int lr = lane & 15, lq = lane >> 4;
    const int p0 = wave * 16;
    f32x4 acc[8];
#pragma unroll
    for (int j = 0; j < 8; ++j) acc[j] = (f32x4){0.f,0.f,0.f,0.f};
#pragma unroll
    for (int kk = 0; kk < 64; kk += 32) {
        const int ra = p0 + lr;
        bhalf8 af = *(const bhalf8*)&Xt[ra * XT_STR + ((((kk >> 3) + lq) ^ ((ra >> 3) & 7)) << 3)];
#pragma unroll
        for (int j = 0; j < 8; ++j) {
            const int rb = j * 16 + lr;
            bhalf8 bf = *(const bhalf8*)&Bt[rb * XT_STR + ((((kk >> 3) + lq) ^ ((rb >> 3) & 7)) << 3)];
            acc[j] = __builtin_amdgcn_mfma_f32_16x16x32_bf16(af, bf, acc[j], 0, 0, 0);
        }
    }
#pragma unroll
    for (int j = 0; j < 8; ++j)
#pragma unroll
        for (int r = 0; r < 4; ++r) {
            int p = p0 + lq * 4 + r;
            int n = j * 16 + lr;
            Sb[(size_t)bhc * 8192 + p * 128 + n] = __float2bfloat16(acc[j][r]);
        }
}

// ---------------------------------------------------------------------------
// Inter-chunk recurrence (16 serial steps): hstart(c)=h; h = decay*h + S_c.
// ---------------------------------------------------------------------------
__global__ __launch_bounds__(256)
void rec_kernel(const __hip_bfloat16* __restrict__ Sb,
                const float* __restrict__ decayg,
                __hip_bfloat16* __restrict__ hst)
{
    const int bh = blockIdx.x >> 3;
    const int sl = blockIdx.x & 7;
    const int off = sl * 1024 + threadIdx.x * 4;
    float h0 = 0.f, h1 = 0.f, h2 = 0.f, h3 = 0.f;
    for (int c = 0; c < NCHUNK; ++c) {
        size_t base = ((size_t)bh * NCHUNK + c) * 8192 + off;
        short4v hb;
        hb[0] = f2bs(h0); hb[1] = f2bs(h1); hb[2] = f2bs(h2); hb[3] = f2bs(h3);
        *(short4v*)&hst[base] = hb;
        short4v sv = *(const short4v*)&Sb[base];
        float d = decayg[bh * NCHUNK + c];
        h0 = fmaf(h0, d, s2f(sv[0])); h1 = fmaf(h1, d, s2f(sv[1]));
        h2 = fmaf(h2, d, s2f(sv[2])); h3 = fmaf(h3, d, s2f(sv[3]));
    }
}

// ---------------------------------------------------------------------------
// Y kernel: [GM -> M in LDS] + [M·X + exp(cum)*C·h^T + Dh*x] + gating.
// Xt uses the tsw() swizzle (same as chunk); zS/Mt stay linear (analyzed
// <=2-way). Writes v bf16 + per-row sum(v^2) atomics.
// ---------------------------------------------------------------------------
__global__ __launch_bounds__(256)
void y_kernel(const __hip_bfloat16* __restrict__ xs_bf,
              const __hip_bfloat16* __restrict__ B_bf,
              const __hip_bfloat16* __restrict__ C_bf,
              const __hip_bfloat16* __restrict__ hst,
              const float* __restrict__ cumg,
              const float* __restrict__ dtp,
              const __hip_bfloat16* __restrict__ zxb,
              const void* __restrict__ Draw, const int* __restrict__ flagp,
              __hip_bfloat16* __restrict__ vbuf, float* __restrict__ rowsum)
{
    __shared__ short Xt[64 * XT_STR];
    __shared__ short zS[64 * XT_STR];
    __shared__ short Mt[64 * XT_STR];
    __shared__ float cumS[Q], dtS[Q];
    const int bhc = blockIdx.x;
    const int c = bhc & 15, h = (bhc >> 4) & 31, b = bhc >> 9;
    const int row0 = b * SEQLEN + c * Q;
    const int isf = *flagp;
    const float Dh = rdin(Draw, h, isf);

    if (threadIdx.x < 64) {
        cumS[threadIdx.x] = cumg[(size_t)bhc * Q + threadIdx.x];
        dtS[threadIdx.x]  = dtp[(size_t)(row0 + threadIdx.x) * NHEADS + h];
    }
#pragma unroll
    for (int i = 0; i < 2; ++i) {
        int seg = threadIdx.x + i * 256;
        int t = seg >> 3, p8 = (seg & 7) * 8;
        int col = ((((t >> 3) ^ (seg & 7)) << 3) | (t & 7));
        bhalf8 v = *(const bhalf8*)&xs_bf[(size_t)(row0 + t) * 2048 + h * 64 + p8];
#pragma unroll
        for (int j = 0; j < 8; ++j)
            Xt[(p8 + j) * XT_STR + col] = v[j];
        bhalf8 zv = *(const bhalf8*)&zxb[(size_t)(row0 + t) * ZX_STR + h * 64 + p8];
        *(bhalf8*)&zS[t * XT_STR + p8] = zv;
    }
    __syncthreads();

    const int wave = threadIdx.x >> 6, lane = threadIdx.x & 63;
    const int lr = lane & 15, lq = lane >> 4;
    const int t0 = wave * 16;

    // GM: G = C·B^T (K=128), masked decay -> Mt (linear layout)
    {
        f32x4 accg[4];
#pragma unroll
        for (int j = 0; j < 4; ++j) accg[j] = (f32x4){0.f,0.f,0.f,0.f};
#pragma unroll
        for (int kk = 0; kk < 128; kk += 32) {
            bhalf8 af = *(const bhalf8*)&C_bf[(size_t)(row0 + t0 + lr) * 128 + kk + lq * 8];
#pragma unroll
            for (int j = 0; j < 4; ++j) {
                bhalf8 bf = *(const bhalf8*)&B_bf[(size_t)(row0 + j * 16 + lr) * 128 + kk + lq * 8];
                accg[j] = __builtin_amdgcn_mfma_f32_16x16x32_bf16(af, bf, accg[j], 0, 0, 0);
            }
        }
#pragma unroll
        for (int j = 0; j < 4; ++j)
#pragma unroll
            for (int r = 0; r < 4; ++r) {
                int t = t0 + lq * 4 + r;
                int s = j * 16 + lr;
                float m = (s <= t) ? accg[j][r] * expf(cumS[t] - cumS[s]) * dtS[s] : 0.f;
                Mt[t * XT_STR + s] = f2bs(m);
            }
    }
    __syncthreads();

    f32x4 acc1[4], acc2[4];
#pragma unroll
    for (int j = 0; j < 4; ++j) { acc1[j] = (f32x4){0.f,0.f,0.f,0.f}; acc2[j] = acc1[j]; }
#pragma unroll
    for (int kk = 0; kk < 64; kk += 32) {
        bhalf8 af = *(const bhalf8*)&Mt[(t0 + lr) * XT_STR + kk + lq * 8];
#pragma unroll
        for (int j = 0; j < 4; ++j) {
            const int rb = j * 16 + lr;
            bhalf8 bf = *(const bhalf8*)&Xt[rb * XT_STR + ((((kk >> 3) + lq) ^ ((rb >> 3) & 7)) << 3)];
            acc1[j] = __builtin_amdgcn_mfma_f32_16x16x32_bf16(af, bf, acc1[j], 0, 0, 0);
        }
    }
#pragma unroll
    for (int kk = 0; kk < 128; kk += 32) {
        bhalf8 af = *(const bhalf8*)&C_bf[(size_t)(row0 + t0 + lr) * 128 + kk + lq * 8];
#pragma unroll
        for (int j = 0; j < 4; ++j) {
            bhalf8 bf = *(const bhalf8*)&hst[(size_t)bhc * 8192 + (j * 16 + lr) * 128 + kk + lq * 8];
            acc2[j] = __builtin_amdgcn_mfma_f32_16x16x32_bf16(af, bf, acc2[j], 0, 0, 0);
        }
    }
    float ex[4];
#pragma unroll
    for (int r = 0; r < 4; ++r) ex[r] = expf(cumS[t0 + lq * 4 + r]);

    float vv[4][4];
    float s2[4] = {0.f, 0.f, 0.f, 0.f};
#pragma unroll
    for (int j = 0; j < 4; ++j)
#pragma unroll
        for (int r = 0; r < 4; ++r) {
            int t = t0 + lq * 4 + r;
            int p = j * 16 + lr;
            float xv = s2f(Xt[p * XT_STR + tsw(p, t)]);
            float y = acc1[j][r] + ex[r] * acc2[j][r] + Dh * xv;
            float zz = s2f(zS[t * XT_STR + p]);
            float v = y * (zz / (1.f + expf(-zz)));
            vv[j][r] = v;
            s2[r] += v * v;
        }
#pragma unroll
    for (int r = 0; r < 4; ++r) {
        s2[r] += __shfl_xor(s2[r], 1);
        s2[r] += __shfl_xor(s2[r], 2);
        s2[r] += __shfl_xor(s2[r], 4);
        s2[r] += __shfl_xor(s2[r], 8);
    }
    if (lr == 0)
#pragma unroll
        for (int r = 0; r < 4; ++r)
            atomicAdd(&rowsum[row0 + t0 + lq * 4 + r], s2[r]);

    __syncthreads();
#pragma unroll
    for (int j = 0; j < 4; ++j)
#pragma unroll
        for (int r = 0; r < 4; ++r)
            zS[(t0 + lq * 4 + r) * XT_STR + j * 16 + lr] = f2bs(vv[j][r]);
    __syncthreads();
#pragma unroll
    for (int i = 0; i < 2; ++i) {
        int seg = threadIdx.x + i * 256;
        int t = seg >> 3, p8 = (seg & 7) * 8;
        bhalf8 o = *(const bhalf8*)&zS[t * XT_STR + p8];
        *(bhalf8*)&vbuf[(size_t)(row0 + t) * D_INNER + h * 64 + p8] = o;
    }
}

extern "C" void kernel_launch(void* const* d_in, const int* in_sizes, int n_in,
                              void* d_out, int out_size, void* d_ws, size_t ws_size,
                              hipStream_t stream)
{
    const void* x_raw    = d_in[0];
    const void* inw_raw  = d_in[1];
    const void* convw    = d_in[2];
    const void* convb    = d_in[3];
    const void* dtb      = d_in[4];
    const void* Alog     = d_in[5];
    const void* Dsk      = d_in[6];
    const void* normw    = d_in[7];
    const void* outw_raw = d_in[8];

    char* ws = (char*)d_ws;
    size_t off = 0;
    int* flag = (int*)(ws + off);                      off += 256;
    float* rowsum = (float*)(ws + off);                off += (size_t)NROWS * 4;
    __hip_bfloat16* xb    = (__hip_bfloat16*)(ws+off); off += (size_t)NROWS * D_MODEL * 2;
    __hip_bfloat16* inwb  = (__hip_bfloat16*)(ws+off); off += (size_t)4384 * D_MODEL * 2;
    __hip_bfloat16* outwb = (__hip_bfloat16*)(ws+off); off += (size_t)D_MODEL * D_INNER * 2;
    __hip_bfloat16* zxb   = (__hip_bfloat16*)(ws+off); off += (size_t)NROWS * ZX_STR * 2;
    __hip_bfloat16* xs_bf = (__hip_bfloat16*)(ws+off); off += (size_t)NROWS * 2048 * 2;
    __hip_bfloat16* B_bf  = (__hip_bfloat16*)(ws+off); off += (size_t)NROWS * 128 * 2;
    __hip_bfloat16* C_bf  = (__hip_bfloat16*)(ws+off); off += (size_t)NROWS * 128 * 2;
    float* dtp   = (float*)(ws+off);                   off += (size_t)NROWS * NHEADS * 4;
    float* cumg  = (float*)(ws+off);                   off += (size_t)1024 * Q * 4;
    float* decayg= (float*)(ws+off);                   off += (size_t)1024 * 4;
    __hip_bfloat16* hst   = (__hip_bfloat16*)(ws+off); off += (size_t)1024 * 8192 * 2;
    __hip_bfloat16* Sb    = (__hip_bfloat16*)(ws+off); off += (size_t)1024 * 8192 * 2;
    __hip_bfloat16* vbuf = Sb;   // Sb dead after rec_kernel, before y writes

    // 1. normalize (+ inline dtype vote; skips x/W copies when already bf16)
    to_bf16_all<<<(XN8+WN8+ON8)/256, 256, 0, stream>>>(x_raw, inw_raw, outw_raw,
                                                       normw, xb, inwb, outwb, flag);
    // 2. in_proj: reads raw directly when inputs are bf16
    gemm_bt<0,64,128,1,4><<<dim3(34, 32), 256, 0, stream>>>(
        xb, x_raw, inwb, inw_raw, zxb, nullptr, nullptr, nullptr, flag,
        D_MODEL, ZX_STR);
    // 3. conv (blocks 0-255) + dt (blocks 256-511)
    convdt<<<512, 256, 0, stream>>>(zxb, convw, convb, x_raw, inw_raw, dtb, flag,
                                    xs_bf, B_bf, C_bf, dtp);
    // 4. cum scan + S (swizzled transposes)
    chunk_kernel<<<1024, 256, 0, stream>>>(xs_bf, B_bf, dtp, Alog, flag,
                                           cumg, decayg, Sb, rowsum);
    // 5. inter-chunk recurrence
    rec_kernel<<<512, 256, 0, stream>>>(Sb, decayg, hst);
    // 6. GM (LDS) + outputs + gating
    y_kernel<<<1024, 256, 0, stream>>>(xs_bf, B_bf, C_bf, hst, cumg, dtp, zxb,
                                       Dsk, flag, vbuf, rowsum);
    // 7. out_proj + fused RMS scale + residual (W always canonical: norm fold)
    gemm_bt<1,64,64,2,2><<<dim3(16, 32), 256, 0, stream>>>(
        vbuf, nullptr, outwb, nullptr, nullptr, x_raw, d_out, rowsum, flag,
        D_INNER, D_MODEL);
}